// Round 5
// baseline (260.483 us; speedup 1.0000x reference)
//
#include <hip/hip_runtime.h>
#include <stdint.h>

// B=4, T=2048, C=1024, H=16, d_k=64. fp32 in/out, bf16 MFMA compute.

typedef __bf16 bf16_t;
typedef __bf16 bf16x4 __attribute__((ext_vector_type(4)));
typedef __bf16 bf16x8 __attribute__((ext_vector_type(8)));
typedef float f32x4 __attribute__((ext_vector_type(4)));

#define LOG2E 1.44269504088896340736f
#define QSCALE (0.125f * LOG2E)  // folded into Q at GEMM1 epilogue

__device__ __forceinline__ void gl_lds16(const void* g, void* l) {
  __builtin_amdgcn_global_load_lds(
      (const __attribute__((address_space(1))) unsigned int*)g,
      (__attribute__((address_space(3))) unsigned int*)l, 16, 0, 0);
}

__device__ __forceinline__ f32x4 mfma16(bf16x8 a, bf16x8 b, f32x4 c) {
  return __builtin_amdgcn_mfma_f32_16x16x32_bf16(a, b, c, 0, 0, 0);
}

// ---------------- fp32 -> bf16 vectorized convert ----------------
__global__ __launch_bounds__(256) void k_cvt_bf16(const float* __restrict__ in,
                                                  bf16_t* __restrict__ out, int n4) {
  int i = blockIdx.x * 256 + threadIdx.x;
  int step = gridDim.x * 256;
  for (; i < n4; i += step) {
    f32x4 v = reinterpret_cast<const f32x4*>(in)[i];
    bf16x4 o;
    o[0] = (bf16_t)v[0]; o[1] = (bf16_t)v[1];
    o[2] = (bf16_t)v[2]; o[3] = (bf16_t)v[3];
    reinterpret_cast<bf16x4*>(out)[i] = o;
  }
}

// ------------- fp32 [R][Cc] -> bf16 [Cc][R] tiled transpose -------------
__global__ __launch_bounds__(256) void k_transpose_cvt(const float* __restrict__ in,
                                                       bf16_t* __restrict__ out,
                                                       int R, int Cc) {
  __shared__ float tile[64][65];
  const int tid = threadIdx.x;
  const int c0 = blockIdx.x * 64, r0 = blockIdx.y * 64;
  const int rr = tid >> 4, cc = (tid & 15) * 4;
#pragma unroll
  for (int i = 0; i < 4; i++) {
    f32x4 v = *reinterpret_cast<const f32x4*>(&in[(size_t)(r0 + rr + i * 16) * Cc + c0 + cc]);
    tile[rr + i * 16][cc + 0] = v[0];
    tile[rr + i * 16][cc + 1] = v[1];
    tile[rr + i * 16][cc + 2] = v[2];
    tile[rr + i * 16][cc + 3] = v[3];
  }
  __syncthreads();
  const int cr = tid >> 2, kb = (tid & 3) * 16;
#pragma unroll
  for (int j4 = 0; j4 < 4; j4++) {
    bf16x4 o;
#pragma unroll
    for (int jj = 0; jj < 4; jj++) o[jj] = (bf16_t)tile[kb + j4 * 4 + jj][cr];
    *reinterpret_cast<bf16x4*>(&out[(size_t)(c0 + cr) * R + r0 + kb + j4 * 4]) = o;
  }
}

// ------- bf16 [B*T][1024] (h-major cols) -> vT [B*H][64][2048] transpose -------
__global__ __launch_bounds__(256) void k_transpose_v(const bf16_t* __restrict__ v,
                                                     bf16_t* __restrict__ vT) {
  __shared__ bf16_t tile[64 * 64];
  const int tid = threadIdx.x;
  const int bh = blockIdx.y;
  const int b = bh >> 4, h = bh & 15;
  const int t0 = blockIdx.x * 64;
#pragma unroll
  for (int i = 0; i < 2; i++) {
    int c = tid + 256 * i;
    int tl = c >> 3, ch = c & 7;
    bf16x8 val = *reinterpret_cast<const bf16x8*>(
        &v[(size_t)(b * 2048 + t0 + tl) * 1024 + h * 64 + ch * 8]);
    int sw = (ch ^ (tl & 7) ^ (tl >> 3)) & 7;
    *reinterpret_cast<bf16x8*>(&tile[tl * 64 + sw * 8]) = val;
  }
  __syncthreads();
#pragma unroll
  for (int i = 0; i < 2; i++) {
    int c = tid + 256 * i;
    int d = c >> 3, tc = c & 7;
    bf16x8 o;
#pragma unroll
    for (int j = 0; j < 8; j++) {
      int t = tc * 8 + j;
      int sw = ((d >> 3) ^ (t & 7) ^ (t >> 3)) & 7;
      o[j] = tile[t * 64 + sw * 8 + (d & 7)];
    }
    *reinterpret_cast<bf16x8*>(&vT[((size_t)bh * 64 + d) * 2048 + t0 + tc * 8]) = o;
  }
}

// ---------------- bf16 GEMM: C[M][N] = A[M][K] * Bt[N][K]^T ----------------
// 3-deep LDS pipeline with counted vmcnt (T4): stage(t+2) after the data-ready
// barrier of t; single raw s_barrier per K-step; vmcnt(4) except last iter.
// MODE 1: QKV epilogue -> Q (scaled) + K to qk[M][2048]; V to vb[M][1024]
// MODE 2: fp32 C[M][N]
template <int MODE>
__global__ __launch_bounds__(256) void k_gemm(const bf16_t* __restrict__ A,
                                              const bf16_t* __restrict__ Bt,
                                              void* __restrict__ C0, void* __restrict__ C1,
                                              int M, int N, int K, int nbx) {
  constexpr int BM = 128, BN = 128, BK = 32;
  __shared__ bf16_t a_sh[3][BM * BK];
  __shared__ bf16_t b_sh[3][BN * BK];
  const int tid = threadIdx.x;
  const int wave = tid >> 6, lane = tid & 63;
  const int g = lane >> 4, lr = lane & 15;
  const int wm = wave >> 1, wn = wave & 1;
  const int nblk = gridDim.x;
  const int swid = (blockIdx.x & 7) * (nblk >> 3) + (blockIdx.x >> 3);
  const int m0 = (swid / nbx) * BM, n0 = (swid % nbx) * BN;

  const bf16_t* ag[2];
  const bf16_t* bg[2];
#pragma unroll
  for (int i = 0; i < 2; i++) {
    int c = tid + 256 * i;
    ag[i] = A + (size_t)(m0 + (c >> 2)) * K + (c & 3) * 8;
    bg[i] = Bt + (size_t)(n0 + (c >> 2)) * K + (c & 3) * 8;
  }

  f32x4 acc[4][4];
#pragma unroll
  for (int i = 0; i < 4; i++)
#pragma unroll
    for (int j = 0; j < 4; j++) acc[i][j] = (f32x4){0.f, 0.f, 0.f, 0.f};

  auto stage = [&](int buf) {
#pragma unroll
    for (int i = 0; i < 2; i++) {
      gl_lds16(ag[i], &a_sh[buf][(tid + 256 * i) * 8]);
      gl_lds16(bg[i], &b_sh[buf][(tid + 256 * i) * 8]);
      ag[i] += BK;
      bg[i] += BK;
    }
  };

  stage(0);
  stage(1);
  const int nK = K / BK;
  int buf = 0;
  for (int it = 0; it < nK; ++it) {
    if (it < nK - 1) asm volatile("s_waitcnt vmcnt(4)" ::: "memory");
    else             asm volatile("s_waitcnt vmcnt(0)" ::: "memory");
    __builtin_amdgcn_s_barrier();
    asm volatile("" ::: "memory");
    if (it + 2 < nK) stage(buf >= 1 ? buf - 1 : buf + 2);  // (buf+2)%3

    bf16x8 af[4], bfr[4];
#pragma unroll
    for (int mi = 0; mi < 4; mi++)
      af[mi] = *reinterpret_cast<const bf16x8*>(&a_sh[buf][(wm * 64 + mi * 16 + lr) * BK + g * 8]);
#pragma unroll
    for (int ni = 0; ni < 4; ni++)
      bfr[ni] = *reinterpret_cast<const bf16x8*>(&b_sh[buf][(wn * 64 + ni * 16 + lr) * BK + g * 8]);
    __builtin_amdgcn_s_setprio(1);
#pragma unroll
    for (int mi = 0; mi < 4; mi++)
#pragma unroll
      for (int ni = 0; ni < 4; ni++) acc[mi][ni] = mfma16(af[mi], bfr[ni], acc[mi][ni]);
    __builtin_amdgcn_s_setprio(0);
    asm volatile("" ::: "memory");
    buf = (buf < 2) ? buf + 1 : 0;
  }

#pragma unroll
  for (int mi = 0; mi < 4; mi++) {
#pragma unroll
    for (int ni = 0; ni < 4; ni++) {
      const int mb = m0 + wm * 64 + mi * 16 + g * 4;
      const int nb = n0 + wn * 64 + ni * 16;
      if constexpr (MODE == 2) {
        float* C = (float*)C0;
#pragma unroll
        for (int r = 0; r < 4; r++) C[(size_t)(mb + r) * N + nb + lr] = acc[mi][ni][r];
      } else {
        if (nb < 2048) {
          const float scl = (nb < 1024) ? QSCALE : 1.0f;
          bf16_t* qk = (bf16_t*)C0;
#pragma unroll
          for (int r = 0; r < 4; r++)
            qk[(size_t)(mb + r) * 2048 + nb + lr] = (bf16_t)(acc[mi][ni][r] * scl);
        } else {
          bf16_t* vb = (bf16_t*)C1;  // [M][1024], coalesced; transposed later
#pragma unroll
          for (int r = 0; r < 4; r++)
            vb[(size_t)(mb + r) * 1024 + (nb - 2048) + lr] = (bf16_t)acc[mi][ni][r];
        }
      }
    }
  }
}

// ---------------- causal flash attention, bf16 MFMA ----------------
// Swapped QK^T in-lane softmax; defer-max; masked-tile skip; 3-deep counted-vmcnt
// K/V pipeline (one raw s_barrier per tile).
__global__ __launch_bounds__(256) void k_attn(const bf16_t* __restrict__ qk,
                                              const bf16_t* __restrict__ vT,
                                              bf16_t* __restrict__ out) {
  constexpr int T = 2048;
  constexpr int PST = 72;
  __shared__ bf16_t k_sh[3][64 * 64];
  __shared__ bf16_t v_sh[3][64 * 64];
  __shared__ bf16_t p_sh[4][32 * PST];
  const int tid = threadIdx.x;
  const int wave = tid >> 6, lane = tid & 63;
  const int g = lane >> 4, lr = lane & 15;

  const int flat = blockIdx.x;
  const int qt = 15 - (flat >> 6);
  const int s6 = flat & 63;
  const int bh = (s6 & 7) * 8 + (s6 >> 3);
  const int b = bh >> 4, h = bh & 15;
  const int q0w = qt * 128 + wave * 32;

  bf16x8 qf[2][2];
#pragma unroll
  for (int rb = 0; rb < 2; rb++) {
    const bf16_t* Qr = qk + (size_t)(b * T + q0w + rb * 16 + lr) * 2048 + h * 64;
    qf[rb][0] = *reinterpret_cast<const bf16x8*>(Qr + g * 8);
    qf[rb][1] = *reinterpret_cast<const bf16x8*>(Qr + 32 + g * 8);
  }

  f32x4 acc_o[2][4];
#pragma unroll
  for (int rb = 0; rb < 2; rb++)
#pragma unroll
    for (int dt = 0; dt < 4; dt++) acc_o[rb][dt] = (f32x4){0.f, 0.f, 0.f, 0.f};
  float mrow[2] = {-1e30f, -1e30f};
  float lrow[2] = {0.f, 0.f};

  const int nt = 2 * qt + 2;

  const bf16_t* kg[2];
  const bf16_t* vg[2];
  {
    const bf16_t* Kbase = qk + (size_t)b * T * 2048 + 1024 + h * 64;
    const bf16_t* Vbase = vT + (size_t)bh * 64 * T;
#pragma unroll
    for (int i = 0; i < 2; i++) {
      int c = tid + 256 * i;
      int row = c >> 3, col8 = (c & 7) ^ (row & 7);
      kg[i] = Kbase + (size_t)row * 2048 + col8 * 8;
      vg[i] = Vbase + (size_t)row * T + col8 * 8;
    }
  }

  auto stageT = [&](int bufn) {
#pragma unroll
    for (int i = 0; i < 2; i++) {
      gl_lds16(kg[i], &k_sh[bufn][(tid + 256 * i) * 8]);
      gl_lds16(vg[i], &v_sh[bufn][(tid + 256 * i) * 8]);
      kg[i] += 64 * 2048;
      vg[i] += 64;
    }
  };

  stageT(0);
  stageT(1);  // nt >= 2 always

  int buf = 0;
  for (int t = 0; t < nt; ++t) {
    const int kv0 = t * 64;
    if (t < nt - 1) asm volatile("s_waitcnt vmcnt(4)" ::: "memory");
    else            asm volatile("s_waitcnt vmcnt(0)" ::: "memory");
    __builtin_amdgcn_s_barrier();
    asm volatile("" ::: "memory");
    if (t + 2 < nt) stageT(buf >= 1 ? buf - 1 : buf + 2);  // (buf+2)%3

    if (kv0 <= q0w + 31) {  // skip fully-causally-masked tiles for this wave
      f32x4 s[2][4];
#pragma unroll
      for (int rb = 0; rb < 2; rb++)
#pragma unroll
        for (int kt = 0; kt < 4; kt++) s[rb][kt] = (f32x4){0.f, 0.f, 0.f, 0.f};
      __builtin_amdgcn_s_setprio(1);
#pragma unroll
      for (int kt = 0; kt < 4; kt++) {
        const int row = kt * 16 + lr, sw = row & 7;
        bf16x8 kf0 = *reinterpret_cast<const bf16x8*>(&k_sh[buf][row * 64 + (g ^ sw) * 8]);
        bf16x8 kf1 = *reinterpret_cast<const bf16x8*>(&k_sh[buf][row * 64 + ((4 + g) ^ sw) * 8]);
#pragma unroll
        for (int rb = 0; rb < 2; rb++) {
          s[rb][kt] = mfma16(kf0, qf[rb][0], s[rb][kt]);
          s[rb][kt] = mfma16(kf1, qf[rb][1], s[rb][kt]);
        }
      }
      __builtin_amdgcn_s_setprio(0);

      if (kv0 + 63 > q0w) {  // causal mask on boundary tiles
#pragma unroll
        for (int rb = 0; rb < 2; rb++)
#pragma unroll
          for (int kt = 0; kt < 4; kt++)
#pragma unroll
            for (int r = 0; r < 4; r++)
              if (kv0 + kt * 16 + g * 4 + r > q0w + rb * 16 + lr) s[rb][kt][r] = -1e30f;
      }

#pragma unroll
      for (int rb = 0; rb < 2; rb++) {
        float pm = s[rb][0][0];
#pragma unroll
        for (int kt = 0; kt < 4; kt++)
#pragma unroll
          for (int r = 0; r < 4; r++) pm = fmaxf(pm, s[rb][kt][r]);
        pm = fmaxf(pm, __shfl_xor(pm, 16, 64));
        pm = fmaxf(pm, __shfl_xor(pm, 32, 64));

        unsigned long long need = __ballot(pm > mrow[rb] + 8.0f);
        if (need) {
          float mnew = fmaxf(mrow[rb], pm);
          float alpha = __builtin_amdgcn_exp2f(mrow[rb] - mnew);
          mrow[rb] = mnew;
          lrow[rb] *= alpha;
#pragma unroll
          for (int r = 0; r < 4; r++) {
            int src = (lane & 48) | ((lane >> 2) & 12) | r;
            float ar = __shfl(alpha, src, 64);
#pragma unroll
            for (int dt = 0; dt < 4; dt++) acc_o[rb][dt][r] *= ar;
          }
        }

        float rs = 0.f;
#pragma unroll
        for (int kt = 0; kt < 4; kt++) {
          f32x4 p;
#pragma unroll
          for (int r = 0; r < 4; r++) p[r] = __builtin_amdgcn_exp2f(s[rb][kt][r] - mrow[rb]);
          rs += (p[0] + p[1]) + (p[2] + p[3]);
          bf16x4 pb;
#pragma unroll
          for (int r = 0; r < 4; r++) pb[r] = (bf16_t)p[r];
          *reinterpret_cast<bf16x4*>(&p_sh[wave][(rb * 16 + lr) * PST + kt * 16 + g * 4]) = pb;
        }
        rs += __shfl_xor(rs, 16, 64);
        rs += __shfl_xor(rs, 32, 64);
        lrow[rb] += rs;
      }

      bf16x8 pa[2][2];
#pragma unroll
      for (int rb = 0; rb < 2; rb++) {
        pa[rb][0] = *reinterpret_cast<const bf16x8*>(&p_sh[wave][(rb * 16 + lr) * PST + g * 8]);
        pa[rb][1] =
            *reinterpret_cast<const bf16x8*>(&p_sh[wave][(rb * 16 + lr) * PST + 32 + g * 8]);
      }
      __builtin_amdgcn_s_setprio(1);
#pragma unroll
      for (int dt = 0; dt < 4; dt++) {
        const int drow = dt * 16 + lr, sw = drow & 7;
        bf16x8 v0 = *reinterpret_cast<const bf16x8*>(&v_sh[buf][drow * 64 + (g ^ sw) * 8]);
        bf16x8 v1 = *reinterpret_cast<const bf16x8*>(&v_sh[buf][drow * 64 + ((4 + g) ^ sw) * 8]);
#pragma unroll
        for (int rb = 0; rb < 2; rb++) {
          acc_o[rb][dt] = mfma16(pa[rb][0], v0, acc_o[rb][dt]);
          acc_o[rb][dt] = mfma16(pa[rb][1], v1, acc_o[rb][dt]);
        }
      }
      __builtin_amdgcn_s_setprio(0);
    }
    asm volatile("" ::: "memory");
    buf = (buf < 2) ? buf + 1 : 0;
  }

#pragma unroll
  for (int rb = 0; rb < 2; rb++) {
    const float linv = 1.0f / lrow[rb];
#pragma unroll
    for (int r = 0; r < 4; r++) {
      int src = (lane & 48) | ((lane >> 2) & 12) | r;
      float lq = __shfl(linv, src, 64);
#pragma unroll
      for (int dt = 0; dt < 4; dt++)
        out[(size_t)(b * T + q0w + rb * 16 + g * 4 + r) * 1024 + h * 64 + dt * 16 + lr] =
            (bf16_t)(acc_o[rb][dt][r] * lq);
    }
  }
}

extern "C" void kernel_launch(void* const* d_in, const int* in_sizes, int n_in,
                              void* d_out, int out_size, void* d_ws, size_t ws_size,
                              hipStream_t stream) {
  (void)in_sizes; (void)n_in; (void)out_size; (void)ws_size;
  const float* x = (const float*)d_in[0];
  const float* w_qkv = (const float*)d_in[1];
  const float* w_out = (const float*)d_in[2];
  float* out = (float*)d_out;
  const int T = 2048, C = 1024;
  const int M = 4 * T;  // 8192

  bf16_t* xb = (bf16_t*)d_ws;                    // [M][C]
  bf16_t* wqkvT = xb + (size_t)M * C;            // [3C][C]
  bf16_t* woutT = wqkvT + (size_t)3 * C * C;     // [C][C]
  bf16_t* qkbuf = woutT + (size_t)C * C;         // [M][2C]
  bf16_t* vbuf = qkbuf + (size_t)M * 2 * C;      // [M][C]  (later: attn out)
  bf16_t* vT = vbuf + (size_t)M * C;             // [B*H][64][T]

  k_cvt_bf16<<<2048, 256, 0, stream>>>(x, xb, M * C / 4);
  k_transpose_cvt<<<dim3(3 * C / 64, C / 64), 256, 0, stream>>>(w_qkv, wqkvT, C, 3 * C);
  k_transpose_cvt<<<dim3(C / 64, C / 64), 256, 0, stream>>>(w_out, woutT, C, C);
  k_gemm<1><<<(3 * C / 128) * (M / 128), 256, 0, stream>>>(xb, wqkvT, qkbuf, vbuf, M, 3 * C, C,
                                                           3 * C / 128);
  k_transpose_v<<<dim3(32, 64), 256, 0, stream>>>(vbuf, vT);
  k_attn<<<1024, 256, 0, stream>>>(qkbuf, vT, vbuf);
  k_gemm<2><<<(C / 128) * (M / 128), 256, 0, stream>>>(vbuf, woutT, out, nullptr, M, C, C,
                                                       C / 128);
}

// Round 6
// 259.606 us; speedup vs baseline: 1.0034x; 1.0034x over previous
//
#include <hip/hip_runtime.h>
#include <stdint.h>

// B=4, T=2048, C=1024, H=16, d_k=64. fp32 in/out, bf16 MFMA compute.

typedef __bf16 bf16_t;
typedef __bf16 bf16x4 __attribute__((ext_vector_type(4)));
typedef __bf16 bf16x8 __attribute__((ext_vector_type(8)));
typedef float f32x4 __attribute__((ext_vector_type(4)));

#define LOG2E 1.44269504088896340736f
#define QSCALE (0.125f * LOG2E)  // folded into Q at GEMM1 epilogue

__device__ __forceinline__ void gl_lds16(const void* g, void* l) {
  __builtin_amdgcn_global_load_lds(
      (const __attribute__((address_space(1))) unsigned int*)g,
      (__attribute__((address_space(3))) unsigned int*)l, 16, 0, 0);
}

__device__ __forceinline__ f32x4 mfma16(bf16x8 a, bf16x8 b, f32x4 c) {
  return __builtin_amdgcn_mfma_f32_16x16x32_bf16(a, b, c, 0, 0, 0);
}

// ---------------- fp32 -> bf16 vectorized convert ----------------
__global__ __launch_bounds__(256) void k_cvt_bf16(const float* __restrict__ in,
                                                  bf16_t* __restrict__ out, int n4) {
  int i = blockIdx.x * 256 + threadIdx.x;
  int step = gridDim.x * 256;
  for (; i < n4; i += step) {
    f32x4 v = reinterpret_cast<const f32x4*>(in)[i];
    bf16x4 o;
    o[0] = (bf16_t)v[0]; o[1] = (bf16_t)v[1];
    o[2] = (bf16_t)v[2]; o[3] = (bf16_t)v[3];
    reinterpret_cast<bf16x4*>(out)[i] = o;
  }
}

// ---- fused fp32->bf16 transposes: w_qkv [1024][3072] and w_out [1024][1024] ----
__global__ __launch_bounds__(256) void k_transpose_cvt2(const float* __restrict__ w_qkv,
                                                        const float* __restrict__ w_out,
                                                        bf16_t* __restrict__ outq,
                                                        bf16_t* __restrict__ outo) {
  __shared__ float tile[64][65];
  const int tid = threadIdx.x;
  const int bx = blockIdx.x;
  const float* in = (bx < 48) ? w_qkv : w_out;
  bf16_t* out = (bx < 48) ? outq : outo;
  const int Cc = (bx < 48) ? 3072 : 1024;
  const int c0 = ((bx < 48) ? bx : bx - 48) * 64;
  const int R = 1024;
  const int r0 = blockIdx.y * 64;
  const int rr = tid >> 4, cc = (tid & 15) * 4;
#pragma unroll
  for (int i = 0; i < 4; i++) {
    f32x4 v = *reinterpret_cast<const f32x4*>(&in[(size_t)(r0 + rr + i * 16) * Cc + c0 + cc]);
    tile[rr + i * 16][cc + 0] = v[0];
    tile[rr + i * 16][cc + 1] = v[1];
    tile[rr + i * 16][cc + 2] = v[2];
    tile[rr + i * 16][cc + 3] = v[3];
  }
  __syncthreads();
  const int cr = tid >> 2, kb = (tid & 3) * 16;
#pragma unroll
  for (int j4 = 0; j4 < 4; j4++) {
    bf16x4 o;
#pragma unroll
    for (int jj = 0; jj < 4; jj++) o[jj] = (bf16_t)tile[kb + j4 * 4 + jj][cr];
    *reinterpret_cast<bf16x4*>(&out[(size_t)(c0 + cr) * R + r0 + kb + j4 * 4]) = o;
  }
}

// ------- bf16 [B*T][1024] (h-major cols) -> vT [B*H][64][2048] transpose -------
__global__ __launch_bounds__(256) void k_transpose_v(const bf16_t* __restrict__ v,
                                                     bf16_t* __restrict__ vT) {
  __shared__ bf16_t tile[64 * 64];
  const int tid = threadIdx.x;
  const int bh = blockIdx.y;
  const int b = bh >> 4, h = bh & 15;
  const int t0 = blockIdx.x * 64;
#pragma unroll
  for (int i = 0; i < 2; i++) {
    int c = tid + 256 * i;
    int tl = c >> 3, ch = c & 7;
    bf16x8 val = *reinterpret_cast<const bf16x8*>(
        &v[(size_t)(b * 2048 + t0 + tl) * 1024 + h * 64 + ch * 8]);
    int sw = (ch ^ (tl & 7) ^ (tl >> 3)) & 7;
    *reinterpret_cast<bf16x8*>(&tile[tl * 64 + sw * 8]) = val;
  }
  __syncthreads();
#pragma unroll
  for (int i = 0; i < 2; i++) {
    int c = tid + 256 * i;
    int d = c >> 3, tc = c & 7;
    bf16x8 o;
#pragma unroll
    for (int j = 0; j < 8; j++) {
      int t = tc * 8 + j;
      int sw = ((d >> 3) ^ (t & 7) ^ (t >> 3)) & 7;
      o[j] = tile[t * 64 + sw * 8 + (d & 7)];
    }
    *reinterpret_cast<bf16x8*>(&vT[((size_t)bh * 64 + d) * 2048 + t0 + tc * 8]) = o;
  }
}

// ---------------- bf16 GEMM: C[M][N] = A[M][K] * Bt[N][K]^T ----------------
// 3-deep counted-vmcnt pipeline + T2 LDS swizzle:
//   LDS chunk (row, c8) holds global chunk c8 ^ ((row>>1)&3)  [linear dest,
//   pre-swizzled SOURCE per rule 21]; reads XOR the same involution ->
//   2 lanes/bank-quad = conflict-free ds_read_b128 (was 8-way).
// MODE 1: QKV epilogue -> Q (scaled) + K to qk[M][2048]; V to vb[M][1024]
// MODE 2: fp32 C[M][N]
template <int MODE>
__global__ __launch_bounds__(256) void k_gemm(const bf16_t* __restrict__ A,
                                              const bf16_t* __restrict__ Bt,
                                              void* __restrict__ C0, void* __restrict__ C1,
                                              int M, int N, int K, int nbx) {
  constexpr int BM = 128, BN = 128, BK = 32;
  __shared__ bf16_t a_sh[3][BM * BK];
  __shared__ bf16_t b_sh[3][BN * BK];
  const int tid = threadIdx.x;
  const int wave = tid >> 6, lane = tid & 63;
  const int g = lane >> 4, lr = lane & 15;
  const int wm = wave >> 1, wn = wave & 1;
  const int nblk = gridDim.x;
  const int swid = (blockIdx.x & 7) * (nblk >> 3) + (blockIdx.x >> 3);
  const int m0 = (swid / nbx) * BM, n0 = (swid % nbx) * BN;

  const bf16_t* ag[2];
  const bf16_t* bg[2];
#pragma unroll
  for (int i = 0; i < 2; i++) {
    int c = tid + 256 * i;
    int row = c >> 2, ch = c & 3;
    int chs = ch ^ ((row >> 1) & 3);  // inverse-swizzled global source
    ag[i] = A + (size_t)(m0 + row) * K + chs * 8;
    bg[i] = Bt + (size_t)(n0 + row) * K + chs * 8;
  }

  f32x4 acc[4][4];
#pragma unroll
  for (int i = 0; i < 4; i++)
#pragma unroll
    for (int j = 0; j < 4; j++) acc[i][j] = (f32x4){0.f, 0.f, 0.f, 0.f};

  auto stage = [&](int buf) {
#pragma unroll
    for (int i = 0; i < 2; i++) {
      gl_lds16(ag[i], &a_sh[buf][(tid + 256 * i) * 8]);
      gl_lds16(bg[i], &b_sh[buf][(tid + 256 * i) * 8]);
      ag[i] += BK;
      bg[i] += BK;
    }
  };

  stage(0);
  stage(1);
  const int nK = K / BK;
  const int swz = (lr >> 1) & 3;  // = (fragment_row>>1)&3 since frag bases are %16==0
  int buf = 0;
  for (int it = 0; it < nK; ++it) {
    if (it < nK - 1) asm volatile("s_waitcnt vmcnt(4)" ::: "memory");
    else             asm volatile("s_waitcnt vmcnt(0)" ::: "memory");
    __builtin_amdgcn_s_barrier();
    asm volatile("" ::: "memory");
    if (it + 2 < nK) stage(buf >= 1 ? buf - 1 : buf + 2);  // (buf+2)%3

    bf16x8 af[4], bfr[4];
#pragma unroll
    for (int mi = 0; mi < 4; mi++)
      af[mi] = *reinterpret_cast<const bf16x8*>(
          &a_sh[buf][(wm * 64 + mi * 16 + lr) * BK + (g ^ swz) * 8]);
#pragma unroll
    for (int ni = 0; ni < 4; ni++)
      bfr[ni] = *reinterpret_cast<const bf16x8*>(
          &b_sh[buf][(wn * 64 + ni * 16 + lr) * BK + (g ^ swz) * 8]);
    __builtin_amdgcn_s_setprio(1);
#pragma unroll
    for (int mi = 0; mi < 4; mi++)
#pragma unroll
      for (int ni = 0; ni < 4; ni++) acc[mi][ni] = mfma16(af[mi], bfr[ni], acc[mi][ni]);
    __builtin_amdgcn_s_setprio(0);
    asm volatile("" ::: "memory");
    buf = (buf < 2) ? buf + 1 : 0;
  }

#pragma unroll
  for (int mi = 0; mi < 4; mi++) {
#pragma unroll
    for (int ni = 0; ni < 4; ni++) {
      const int mb = m0 + wm * 64 + mi * 16 + g * 4;
      const int nb = n0 + wn * 64 + ni * 16;
      if constexpr (MODE == 2) {
        float* C = (float*)C0;
#pragma unroll
        for (int r = 0; r < 4; r++) C[(size_t)(mb + r) * N + nb + lr] = acc[mi][ni][r];
      } else {
        if (nb < 2048) {
          const float scl = (nb < 1024) ? QSCALE : 1.0f;
          bf16_t* qk = (bf16_t*)C0;
#pragma unroll
          for (int r = 0; r < 4; r++)
            qk[(size_t)(mb + r) * 2048 + nb + lr] = (bf16_t)(acc[mi][ni][r] * scl);
        } else {
          bf16_t* vb = (bf16_t*)C1;  // [M][1024], coalesced; transposed later
#pragma unroll
          for (int r = 0; r < 4; r++)
            vb[(size_t)(mb + r) * 1024 + (nb - 2048) + lr] = (bf16_t)acc[mi][ni][r];
        }
      }
    }
  }
}

// ---------------- causal flash attention, bf16 MFMA ----------------
// Swapped QK^T in-lane softmax; defer-max; masked-tile skip; 3-deep counted-vmcnt
// K/V pipeline (one raw s_barrier per tile).
__global__ __launch_bounds__(256) void k_attn(const bf16_t* __restrict__ qk,
                                              const bf16_t* __restrict__ vT,
                                              bf16_t* __restrict__ out) {
  constexpr int T = 2048;
  constexpr int PST = 72;
  __shared__ bf16_t k_sh[3][64 * 64];
  __shared__ bf16_t v_sh[3][64 * 64];
  __shared__ bf16_t p_sh[4][32 * PST];
  const int tid = threadIdx.x;
  const int wave = tid >> 6, lane = tid & 63;
  const int g = lane >> 4, lr = lane & 15;

  const int flat = blockIdx.x;
  const int qt = 15 - (flat >> 6);
  const int s6 = flat & 63;
  const int bh = (s6 & 7) * 8 + (s6 >> 3);
  const int b = bh >> 4, h = bh & 15;
  const int q0w = qt * 128 + wave * 32;

  bf16x8 qf[2][2];
#pragma unroll
  for (int rb = 0; rb < 2; rb++) {
    const bf16_t* Qr = qk + (size_t)(b * T + q0w + rb * 16 + lr) * 2048 + h * 64;
    qf[rb][0] = *reinterpret_cast<const bf16x8*>(Qr + g * 8);
    qf[rb][1] = *reinterpret_cast<const bf16x8*>(Qr + 32 + g * 8);
  }

  f32x4 acc_o[2][4];
#pragma unroll
  for (int rb = 0; rb < 2; rb++)
#pragma unroll
    for (int dt = 0; dt < 4; dt++) acc_o[rb][dt] = (f32x4){0.f, 0.f, 0.f, 0.f};
  float mrow[2] = {-1e30f, -1e30f};
  float lrow[2] = {0.f, 0.f};

  const int nt = 2 * qt + 2;

  const bf16_t* kg[2];
  const bf16_t* vg[2];
  {
    const bf16_t* Kbase = qk + (size_t)b * T * 2048 + 1024 + h * 64;
    const bf16_t* Vbase = vT + (size_t)bh * 64 * T;
#pragma unroll
    for (int i = 0; i < 2; i++) {
      int c = tid + 256 * i;
      int row = c >> 3, col8 = (c & 7) ^ (row & 7);
      kg[i] = Kbase + (size_t)row * 2048 + col8 * 8;
      vg[i] = Vbase + (size_t)row * T + col8 * 8;
    }
  }

  auto stageT = [&](int bufn) {
#pragma unroll
    for (int i = 0; i < 2; i++) {
      gl_lds16(kg[i], &k_sh[bufn][(tid + 256 * i) * 8]);
      gl_lds16(vg[i], &v_sh[bufn][(tid + 256 * i) * 8]);
      kg[i] += 64 * 2048;
      vg[i] += 64;
    }
  };

  stageT(0);
  stageT(1);  // nt >= 2 always

  int buf = 0;
  for (int t = 0; t < nt; ++t) {
    const int kv0 = t * 64;
    if (t < nt - 1) asm volatile("s_waitcnt vmcnt(4)" ::: "memory");
    else            asm volatile("s_waitcnt vmcnt(0)" ::: "memory");
    __builtin_amdgcn_s_barrier();
    asm volatile("" ::: "memory");
    if (t + 2 < nt) stageT(buf >= 1 ? buf - 1 : buf + 2);  // (buf+2)%3

    if (kv0 <= q0w + 31) {  // skip fully-causally-masked tiles for this wave
      f32x4 s[2][4];
#pragma unroll
      for (int rb = 0; rb < 2; rb++)
#pragma unroll
        for (int kt = 0; kt < 4; kt++) s[rb][kt] = (f32x4){0.f, 0.f, 0.f, 0.f};
      __builtin_amdgcn_s_setprio(1);
#pragma unroll
      for (int kt = 0; kt < 4; kt++) {
        const int row = kt * 16 + lr, sw = row & 7;
        bf16x8 kf0 = *reinterpret_cast<const bf16x8*>(&k_sh[buf][row * 64 + (g ^ sw) * 8]);
        bf16x8 kf1 = *reinterpret_cast<const bf16x8*>(&k_sh[buf][row * 64 + ((4 + g) ^ sw) * 8]);
#pragma unroll
        for (int rb = 0; rb < 2; rb++) {
          s[rb][kt] = mfma16(kf0, qf[rb][0], s[rb][kt]);
          s[rb][kt] = mfma16(kf1, qf[rb][1], s[rb][kt]);
        }
      }
      __builtin_amdgcn_s_setprio(0);

      if (kv0 + 63 > q0w) {  // causal mask on boundary tiles
#pragma unroll
        for (int rb = 0; rb < 2; rb++)
#pragma unroll
          for (int kt = 0; kt < 4; kt++)
#pragma unroll
            for (int r = 0; r < 4; r++)
              if (kv0 + kt * 16 + g * 4 + r > q0w + rb * 16 + lr) s[rb][kt][r] = -1e30f;
      }

#pragma unroll
      for (int rb = 0; rb < 2; rb++) {
        float pm = s[rb][0][0];
#pragma unroll
        for (int kt = 0; kt < 4; kt++)
#pragma unroll
          for (int r = 0; r < 4; r++) pm = fmaxf(pm, s[rb][kt][r]);
        pm = fmaxf(pm, __shfl_xor(pm, 16, 64));
        pm = fmaxf(pm, __shfl_xor(pm, 32, 64));

        unsigned long long need = __ballot(pm > mrow[rb] + 8.0f);
        if (need) {
          float mnew = fmaxf(mrow[rb], pm);
          float alpha = __builtin_amdgcn_exp2f(mrow[rb] - mnew);
          mrow[rb] = mnew;
          lrow[rb] *= alpha;
#pragma unroll
          for (int r = 0; r < 4; r++) {
            int src = (lane & 48) | ((lane >> 2) & 12) | r;
            float ar = __shfl(alpha, src, 64);
#pragma unroll
            for (int dt = 0; dt < 4; dt++) acc_o[rb][dt][r] *= ar;
          }
        }

        float rs = 0.f;
#pragma unroll
        for (int kt = 0; kt < 4; kt++) {
          f32x4 p;
#pragma unroll
          for (int r = 0; r < 4; r++) p[r] = __builtin_amdgcn_exp2f(s[rb][kt][r] - mrow[rb]);
          rs += (p[0] + p[1]) + (p[2] + p[3]);
          bf16x4 pb;
#pragma unroll
          for (int r = 0; r < 4; r++) pb[r] = (bf16_t)p[r];
          *reinterpret_cast<bf16x4*>(&p_sh[wave][(rb * 16 + lr) * PST + kt * 16 + g * 4]) = pb;
        }
        rs += __shfl_xor(rs, 16, 64);
        rs += __shfl_xor(rs, 32, 64);
        lrow[rb] += rs;
      }

      bf16x8 pa[2][2];
#pragma unroll
      for (int rb = 0; rb < 2; rb++) {
        pa[rb][0] = *reinterpret_cast<const bf16x8*>(&p_sh[wave][(rb * 16 + lr) * PST + g * 8]);
        pa[rb][1] =
            *reinterpret_cast<const bf16x8*>(&p_sh[wave][(rb * 16 + lr) * PST + 32 + g * 8]);
      }
      __builtin_amdgcn_s_setprio(1);
#pragma unroll
      for (int dt = 0; dt < 4; dt++) {
        const int drow = dt * 16 + lr, sw = drow & 7;
        bf16x8 v0 = *reinterpret_cast<const bf16x8*>(&v_sh[buf][drow * 64 + (g ^ sw) * 8]);
        bf16x8 v1 = *reinterpret_cast<const bf16x8*>(&v_sh[buf][drow * 64 + ((4 + g) ^ sw) * 8]);
#pragma unroll
        for (int rb = 0; rb < 2; rb++) {
          acc_o[rb][dt] = mfma16(pa[rb][0], v0, acc_o[rb][dt]);
          acc_o[rb][dt] = mfma16(pa[rb][1], v1, acc_o[rb][dt]);
        }
      }
      __builtin_amdgcn_s_setprio(0);
    }
    asm volatile("" ::: "memory");
    buf = (buf < 2) ? buf + 1 : 0;
  }

#pragma unroll
  for (int rb = 0; rb < 2; rb++) {
    const float linv = 1.0f / lrow[rb];
#pragma unroll
    for (int r = 0; r < 4; r++) {
      int src = (lane & 48) | ((lane >> 2) & 12) | r;
      float lq = __shfl(linv, src, 64);
#pragma unroll
      for (int dt = 0; dt < 4; dt++)
        out[(size_t)(b * T + q0w + rb * 16 + g * 4 + r) * 1024 + h * 64 + dt * 16 + lr] =
            (bf16_t)(acc_o[rb][dt][r] * lq);
    }
  }
}

extern "C" void kernel_launch(void* const* d_in, const int* in_sizes, int n_in,
                              void* d_out, int out_size, void* d_ws, size_t ws_size,
                              hipStream_t stream) {
  (void)in_sizes; (void)n_in; (void)out_size; (void)ws_size;
  const float* x = (const float*)d_in[0];
  const float* w_qkv = (const float*)d_in[1];
  const float* w_out = (const float*)d_in[2];
  float* out = (float*)d_out;
  const int T = 2048, C = 1024;
  const int M = 4 * T;  // 8192

  bf16_t* xb = (bf16_t*)d_ws;                    // [M][C]
  bf16_t* wqkvT = xb + (size_t)M * C;            // [3C][C]
  bf16_t* woutT = wqkvT + (size_t)3 * C * C;     // [C][C]
  bf16_t* qkbuf = woutT + (size_t)C * C;         // [M][2C]
  bf16_t* vbuf = qkbuf + (size_t)M * 2 * C;      // [M][C]  (later: attn out)
  bf16_t* vT = vbuf + (size_t)M * C;             // [B*H][64][T]

  k_cvt_bf16<<<2048, 256, 0, stream>>>(x, xb, M * C / 4);
  k_transpose_cvt2<<<dim3(64, 16), 256, 0, stream>>>(w_qkv, w_out, wqkvT, woutT);
  k_gemm<1><<<(3 * C / 128) * (M / 128), 256, 0, stream>>>(xb, wqkvT, qkbuf, vbuf, M, 3 * C, C,
                                                           3 * C / 128);
  k_transpose_v<<<dim3(32, 64), 256, 0, stream>>>(vbuf, vT);
  k_attn<<<1024, 256, 0, stream>>>(qkbuf, vT, vbuf);
  k_gemm<2><<<(C / 128) * (M / 128), 256, 0, stream>>>(vbuf, woutT, out, nullptr, M, C, C,
                                                       C / 128);
}